// Round 19
// baseline (126.512 us; speedup 1.0000x reference)
//
#include <hip/hip_runtime.h>
#include <hip/hip_bf16.h>
#include <math.h>

// KoLeo loss, MI355X. Fused normalize+pack -> MFMA gram two-sided row-max
// (symmetric triangular walk, never materializes the gram) -> log/mean.
//
// v18: BARRIER-FREE, LDS-FREE kmax. v7's verified structure (mfma(af_j,
// bfr_i): i on LANE axis -> rmax is 2 scalars; j on REG axis -> DPP
// log-fold per unit), with v7's failures fixed:
//   - block-coherent j-walk: all 4 waves of a block walk the SAME unit
//     sequence (v16b's 512-block triangular partition), each owning a
//     64-row i-slice -> same global traffic pattern as the LDS version
//     (j-tile L1/L2-served), unlike v7's 2048 private walks (165MB FETCH).
//   - regs fit 2 waves/SIMD: bfr 128 + af 64 + acc 32 + scalars ~ 244.
// No __syncthreads, no vmcnt scaffold, no global_load_lds: waves free-run
// and desync -> MFMA/VALU/VMEM overlap across the SIMD's 2 waves (m114),
// which the 2-phase barrier loop structurally prevented (8 variants all
// pinned at 31-38% MfmaUtil).
//
// F layout (32-row tiles): chunk(t32,ks,lane) = t32*1024 + ks*64 + lane,
//   16B chunk = 8 bf16 of xn[t32*32 + (lane&31)][ks*16 + (lane>>5)*8 .. +7].
// D = mfma(af, bfr): col=lane&31 -> i_local, row=(r&3)+8(r>>2)+4(lane>>5)
// -> j_local (v7, verified absmax 0).

typedef __attribute__((ext_vector_type(8))) short bf16x8;    // 8 bf16 = 4 VGPR
typedef __attribute__((ext_vector_type(16))) float f32x16;   // 32x32 acc

#define NROWS 16384
#define NDIM  256
#define NBLK  512
// units: ib in [0,64) (256-row i-panel), jt in [8*ib, 512) (32-row j-tile)
// P(ib) = ib*(516-4ib); total 16640 units; 32.5 per block.

// ---------------- K0: fused row-norm + pack + rowcand zero ----------------
__device__ inline unsigned bf_rne(float f) {
    union { float f; unsigned u; } c; c.f = f;
    return (c.u + 0x7FFFu + ((c.u >> 16) & 1u)) >> 16;
}
__device__ inline unsigned pack2(float lo, float hi) {
    return bf_rne(lo) | (bf_rne(hi) << 16);
}

__global__ __launch_bounds__(256) void knp(const float* __restrict__ x,
                                           uint4* __restrict__ F,
                                           unsigned* __restrict__ rowcand) {
    __shared__ float rnorm[32];
    const int t32 = blockIdx.x;                     // 512 tiles of 32 rows
    const int tid = threadIdx.x;

    if (tid < 32) rowcand[t32 * 32 + tid] = 0u;     // zero my slice

    int row = tid >> 3;                             // 8 threads per row
    int c0  = (tid & 7) * 32;
    const float4* xr = (const float4*)(x + ((size_t)t32 * 32 + row) * NDIM + c0);
    float ss = 0.f;
    #pragma unroll
    for (int q = 0; q < 8; ++q) {
        float4 v = xr[q];
        ss += v.x * v.x + v.y * v.y + v.z * v.z + v.w * v.w;
    }
    ss += __shfl_xor(ss, 1, 64);
    ss += __shfl_xor(ss, 2, 64);
    ss += __shfl_xor(ss, 4, 64);
    if ((tid & 7) == 0) rnorm[row] = 1.0f / fmaxf(sqrtf(ss), 1e-12f);
    __syncthreads();

    #pragma unroll
    for (int q = 0; q < 4; ++q) {                   // 4 fragment chunks each
        int c    = q * 256 + tid;
        int ks   = c >> 6;
        int lane = c & 63;
        int r    = lane & 31;
        int kb   = ks * 16 + (lane >> 5) * 8;
        float s  = rnorm[r];
        const float4* xp = (const float4*)(x + ((size_t)t32 * 32 + r) * NDIM + kb);
        float4 a = xp[0], b2 = xp[1];
        uint4 o;
        o.x = pack2(a.x * s, a.y * s);
        o.y = pack2(a.z * s, a.w * s);
        o.z = pack2(b2.x * s, b2.y * s);
        o.w = pack2(b2.z * s, b2.w * s);
        F[(size_t)t32 * 1024 + c] = o;
    }
}

// ---------------- helpers ----------------
__device__ inline unsigned fkey(float f) {          // order-preserving key
    unsigned u = __builtin_bit_cast(unsigned, f);
    return (u & 0x80000000u) ? ~u : (u | 0x80000000u);
}

template<int CTRL>                                  // DPP rotate within 16-lane row
__device__ inline float dpp_rot(float x) {
    int xi = __builtin_bit_cast(int, x);
    int yi = __builtin_amdgcn_update_dpp(xi, xi, CTRL, 0xF, 0xF, false);
    return __builtin_bit_cast(float, yi);
}

// ---------------- K2: barrier-free symmetric gram + two-sided max ---------
// 512 blocks x 256 threads (4 waves, 2 blocks/CU). Unit = 256i x 32j rows;
// wave w owns the 64-row i-slice {cib*8 + 2w, +1}; all waves share j-walk.
__global__ __launch_bounds__(256, 2) void kmax(const bf16x8* __restrict__ F,
                                               unsigned* __restrict__ rowcand) {
    const int tid  = threadIdx.x;
    const int wid  = tid >> 6;                      // 0..3
    const int lane = tid & 63;
    const int L    = lane & 31;
    const int hi   = lane >> 5;
    const int idx  = lane & 15;

    // XCD-chunked bijective swizzle (512 % 8 == 0)
    const int b    = ((blockIdx.x & 7) << 6) | (blockIdx.x >> 3);
    const int u0   = (b * 65) >> 1;                 // 16640/512 = 32.5
    const int uend = ((b + 1) * 65) >> 1;

    // decode u0 -> (cib, cjt): P(ib) = ib*(516-4ib); jt0(ib) = 8*ib
    int cib = 0;
    while ((cib + 1) * (516 - 4 * (cib + 1)) <= u0) ++cib;
    int cjt = 8 * cib + (u0 - cib * (516 - 4 * cib));

    // hoisted i-fragments: tiles {cib*8 + 2wid, +1}, 128 VGPR
    int myit = cib * 8 + 2 * wid;
    bf16x8 bfr0[16], bfr1[16];
    #pragma unroll
    for (int ks = 0; ks < 16; ++ks) {
        bfr0[ks] = F[(myit + 0) * 1024 + ks * 64 + lane];
        bfr1[ks] = F[(myit + 1) * 1024 + ks * 64 + lane];
    }
    // j-fragments for the first unit (64 VGPR)
    bf16x8 af[16];
    #pragma unroll
    for (int ks = 0; ks < 16; ++ks)
        af[ks] = F[(size_t)cjt * 1024 + ks * 64 + lane];

    float rmax0 = -1e30f, rmax1 = -1e30f;
    // diag: i_local = lane&31 (col); j_local = (r&3)+8*(r>>2)+4*hi (row)
    const bool dvalid = (((L >> 2) & 1) == hi);
    const int  dreg   = (L & 3) | ((L >> 3) << 2);
    const int  jloc   = (idx & 3) + 8 * (idx >> 2) + 4 * hi;  // fold output j

    for (int s = u0; s < uend; ++s) {
        // ---- MFMA: 2 chains (2 waves/SIMD x 2 = 4 chains, pipe-covering) --
        f32x16 c0 = {0.f}, c1 = {0.f};
        #pragma unroll
        for (int ks = 0; ks < 16; ++ks) {
            c0 = __builtin_amdgcn_mfma_f32_32x32x16_bf16(af[ks], bfr0[ks], c0, 0, 0, 0);
            c1 = __builtin_amdgcn_mfma_f32_32x32x16_bf16(af[ks], bfr1[ks], c1, 0, 0, 0);
        }

        // ---- next-unit coords + af prefetch (hidden under EPI VALU) ----
        int nib = cib, njt = cjt + 1;
        if (njt == 512) { if (nib < 63) { ++nib; njt = 8 * nib; } else njt = 511; }
        if (s + 1 < uend) {
            #pragma unroll
            for (int ks = 0; ks < 16; ++ks)
                af[ks] = F[(size_t)njt * 1024 + ks * 64 + lane];
        }

        // ---- EPI: diag mask -> rmax (scalar) + in-place jm ----
        const bool m0 = (cjt == myit), m1 = (cjt == myit + 1);
        #pragma unroll
        for (int r = 0; r < 16; ++r) {
            float v0 = c0[r], v1 = c1[r];
            if (m0 && dvalid && r == dreg) v0 = -1e30f;
            if (m1 && dvalid && r == dreg) v1 = -1e30f;
            rmax0 = fmaxf(rmax0, v0);
            rmax1 = fmaxf(rmax1, v1);
            c0[r] = fmaxf(v0, v1);                  // jm in place
        }
        // log-fold 16 regs -> 1 across the 16-lane row (v7, verified)
        float f8[8];
        #pragma unroll
        for (int r = 0; r < 8; ++r) {
            float t = (idx & 8) ? c0[r + 8] : c0[r];
            f8[r] = fmaxf(t, dpp_rot<0x128>(t));    // row_ror:8
        }
        float f4[4];
        #pragma unroll
        for (int r = 0; r < 4; ++r) {
            float t = (idx & 4) ? f8[r + 4] : f8[r];
            f4[r] = fmaxf(t, dpp_rot<0x124>(t));    // row_ror:4
        }
        float f2a = fmaxf((idx & 2) ? f4[2] : f4[0],
                          dpp_rot<0x122>((idx & 2) ? f4[2] : f4[0]));
        float f2b = fmaxf((idx & 2) ? f4[3] : f4[1],
                          dpp_rot<0x122>((idx & 2) ? f4[3] : f4[1]));
        float f1 = (idx & 1) ? f2b : f2a;
        f1 = fmaxf(f1, dpp_rot<0x121>(f1));         // row_ror:1
        f1 = fmaxf(f1, __shfl_xor(f1, 16, 64));     // merge i-halves
        if (!(lane & 16))
            atomicMax(&rowcand[cjt * 32 + jloc], fkey(f1));

        // ---- i-panel transition ----
        if (nib != cib) {
            float t0 = fmaxf(rmax0, __shfl_xor(rmax0, 32, 64));
            float t1 = fmaxf(rmax1, __shfl_xor(rmax1, 32, 64));
            if (lane < 32) {
                atomicMax(&rowcand[myit * 32 + L],      fkey(t0));
                atomicMax(&rowcand[myit * 32 + 32 + L], fkey(t1));
            }
            rmax0 = rmax1 = -1e30f;
            if (s + 1 < uend) {
                myit = nib * 8 + 2 * wid;
                #pragma unroll
                for (int ks = 0; ks < 16; ++ks) {
                    bfr0[ks] = F[(myit + 0) * 1024 + ks * 64 + lane];
                    bfr1[ks] = F[(myit + 1) * 1024 + ks * 64 + lane];
                }
            }
        }
        cib = nib; cjt = njt;
    }

    // final i-side flush (tiny keys if already flushed at a transition)
    {
        float t0 = fmaxf(rmax0, __shfl_xor(rmax0, 32, 64));
        float t1 = fmaxf(rmax1, __shfl_xor(rmax1, 32, 64));
        if (lane < 32) {
            atomicMax(&rowcand[myit * 32 + L],      fkey(t0));
            atomicMax(&rowcand[myit * 32 + 32 + L], fkey(t1));
        }
    }
}

// ---------------- K3: loss epilogue (2-stage, deterministic) --------------
__global__ __launch_bounds__(256) void kloss1(const unsigned* __restrict__ rowcand,
                                              float* __restrict__ partial) {
    int i = blockIdx.x * 256 + threadIdx.x;         // 64 blocks x 256
    unsigned k = rowcand[i];
    unsigned u = (k & 0x80000000u) ? (k ^ 0x80000000u) : ~k;
    float gv = __builtin_bit_cast(float, u);
    float d = sqrtf(fmaxf(2.f - 2.f * gv, 0.f));
    float acc = logf(d + 1e-8f);
    #pragma unroll
    for (int m = 1; m < 64; m <<= 1) acc += __shfl_xor(acc, m, 64);
    __shared__ float p[4];
    int wid = threadIdx.x >> 6, lane = threadIdx.x & 63;
    if (lane == 0) p[wid] = acc;
    __syncthreads();
    if (threadIdx.x == 0)
        partial[blockIdx.x] = (p[0] + p[1]) + (p[2] + p[3]);
}

__global__ __launch_bounds__(64) void kloss2(const float* __restrict__ partial,
                                             float* __restrict__ out) {
    float acc = partial[threadIdx.x];
    #pragma unroll
    for (int m = 1; m < 64; m <<= 1) acc += __shfl_xor(acc, m, 64);
    if (threadIdx.x == 0) out[0] = -acc / (float)NROWS;
}

extern "C" void kernel_launch(void* const* d_in, const int* in_sizes, int n_in,
                              void* d_out, int out_size, void* d_ws, size_t ws_size,
                              hipStream_t stream) {
    const float* x = (const float*)d_in[0];
    float* out = (float*)d_out;
    char* ws = (char*)d_ws;

    uint4*    F       = (uint4*)ws;                                 // 8 MiB
    unsigned* rowcand = (unsigned*)(ws + 8u * 1024u * 1024u + 65536u); // 64 KiB
    float*    partial = (float*)(ws + 8u * 1024u * 1024u + 131072u);   // 256 B

    knp   <<<NROWS / 32, 256, 0, stream>>>(x, F, rowcand);
    kmax  <<<NBLK, 256, 0, stream>>>((const bf16x8*)F, rowcand);
    kloss1<<<64, 256, 0, stream>>>(rowcand, partial);
    kloss2<<<1, 64, 0, stream>>>(partial, out);
}

// Round 20
// 87.735 us; speedup vs baseline: 1.4420x; 1.4420x over previous
//
#include <hip/hip_runtime.h>
#include <hip/hip_bf16.h>
#include <math.h>

// KoLeo loss, MI355X. Fused normalize+pack -> MFMA gram two-sided row-max
// (symmetric triangular walk, never materializes the gram) -> log/mean.
//
// FINAL (= v16b, best measured: 89.7 us total, kmax 78 us, absmax 0):
//   - kmax: 512 blocks x 4 waves (2 blocks/CU), unit = 256i x 32j,
//     triple-buffer LDS via global_load_lds + counted s_waitcnt vmcnt(5)
//     (stage loads stay in flight across barriers), operand-swapped MFMA
//     (j on lane axis -> 1 atomic j-flush/unit), rm[2][16] i-side maxima
//     folded by DPP only at i-panel transitions, symmetric triangular walk
//     (half the gram), XCD-chunked block swizzle.
//   - aux: fused knp (norm+pack+rowcand-zero in ONE x pass) + 2-stage kloss.
//
// Structural note: 8 escape attempts from this 2-phase barrier loop
// (T15 ping-pong x2 -> VGPR-256 spill storms; barrier-free reg-staged x2
// -> af spills via LDS / FETCH blowup; 2-desynced-blocks x3 + anti-phase
// stagger -> null) all measured at or below this structure's ~78 us kmax.
// MfmaUtil pins at 37% = the 2-phase scaffold ceiling; the 28 us MFMA wall
// requires a full 8-phase co-designed rewrite.
//
// F layout (32-row tiles): chunk(t32,ks,lane) = t32*1024 + ks*64 + lane,
//   16B chunk = 8 bf16 of xn[t32*32 + (lane&31)][ks*16 + (lane>>5)*8 .. +7].
// == mfma_f32_32x32x16_bf16 A/B fragment layout -> linear coalesced staging.
// D = mfma(bfr_i, af_j): col=lane&31 -> j_local, row=(r&3)+8(r>>2)+4(lane>>5)
// -> i_local (verified v8-v18, absmax 0 throughout).

typedef __attribute__((ext_vector_type(8))) short bf16x8;    // 8 bf16 = 4 VGPR
typedef __attribute__((ext_vector_type(16))) float f32x16;   // 32x32 acc

#define NROWS 16384
#define NDIM  256
#define NBLK  512
// units: ib in [0,64) (256-row i-panel), jt in [8*ib, 512) (32-row j-tile)
// P(ib) = ib*(516-4ib); total 16640 units; 32.5 per block.

// ---------------- K0: fused row-norm + pack + rowcand zero ----------------
__device__ inline unsigned bf_rne(float f) {
    union { float f; unsigned u; } c; c.f = f;
    return (c.u + 0x7FFFu + ((c.u >> 16) & 1u)) >> 16;
}
__device__ inline unsigned pack2(float lo, float hi) {
    return bf_rne(lo) | (bf_rne(hi) << 16);
}

__global__ __launch_bounds__(256) void knp(const float* __restrict__ x,
                                           uint4* __restrict__ F,
                                           unsigned* __restrict__ rowcand) {
    __shared__ float rnorm[32];
    const int t32 = blockIdx.x;                     // 512 tiles of 32 rows
    const int tid = threadIdx.x;

    if (tid < 32) rowcand[t32 * 32 + tid] = 0u;     // zero my slice

    int row = tid >> 3;                             // 8 threads per row
    int c0  = (tid & 7) * 32;
    const float4* xr = (const float4*)(x + ((size_t)t32 * 32 + row) * NDIM + c0);
    float ss = 0.f;
    #pragma unroll
    for (int q = 0; q < 8; ++q) {
        float4 v = xr[q];
        ss += v.x * v.x + v.y * v.y + v.z * v.z + v.w * v.w;
    }
    ss += __shfl_xor(ss, 1, 64);
    ss += __shfl_xor(ss, 2, 64);
    ss += __shfl_xor(ss, 4, 64);
    if ((tid & 7) == 0) rnorm[row] = 1.0f / fmaxf(sqrtf(ss), 1e-12f);
    __syncthreads();

    #pragma unroll
    for (int q = 0; q < 4; ++q) {                   // 4 fragment chunks each
        int c    = q * 256 + tid;
        int ks   = c >> 6;
        int lane = c & 63;
        int r    = lane & 31;
        int kb   = ks * 16 + (lane >> 5) * 8;
        float s  = rnorm[r];
        const float4* xp = (const float4*)(x + ((size_t)t32 * 32 + r) * NDIM + kb);
        float4 a = xp[0], b2 = xp[1];
        uint4 o;
        o.x = pack2(a.x * s, a.y * s);
        o.y = pack2(a.z * s, a.w * s);
        o.z = pack2(b2.x * s, b2.y * s);
        o.w = pack2(b2.z * s, b2.w * s);
        F[(size_t)t32 * 1024 + c] = o;
    }
}

// ---------------- helpers ----------------
__device__ inline void stage16(const uint4* __restrict__ g, const uint4* l) {
    __builtin_amdgcn_global_load_lds(
        (const __attribute__((address_space(1))) unsigned*)g,
        (__attribute__((address_space(3))) unsigned*)l, 16, 0, 0);
}

__device__ inline unsigned fkey(float f) {          // order-preserving key
    unsigned u = __builtin_bit_cast(unsigned, f);
    return (u & 0x80000000u) ? ~u : (u | 0x80000000u);
}

template<int CTRL>                                  // DPP rotate within 16-lane row
__device__ inline float dpp_rot(float x) {
    int xi = __builtin_bit_cast(int, x);
    int yi = __builtin_amdgcn_update_dpp(xi, xi, CTRL, 0xF, 0xF, false);
    return __builtin_bit_cast(float, yi);
}

// ---------------- K2: pipelined symmetric gram + two-sided max ------------
// 512 blocks x 256 threads (4 waves, 2 blocks/CU). Unit = 256 i x 32 j rows.
__global__ __launch_bounds__(256, 2) void kmax(const bf16x8* __restrict__ F,
                                               unsigned* __restrict__ rowcand) {
    __shared__ uint4 sbuf[3][1024];                 // 3 x 16KB j-tile buffers
    __shared__ uint4 dump[64];                      // pad-load target (dead)

    const int tid  = threadIdx.x;
    const int wid  = tid >> 6;                      // 0..3
    const int lane = tid & 63;
    const int L    = lane & 31;
    const int hi   = lane >> 5;
    const uint4* F4 = (const uint4*)F;

    // XCD-chunked bijective swizzle (512 % 8 == 0)
    const int b  = ((blockIdx.x & 7) << 6) | (blockIdx.x >> 3);
    // run partition: 16640 units / 512 blocks = 32.5
    const int u0   = (b * 65) >> 1;
    const int uend = ((b + 1) * 65) >> 1;

    // decode u0 -> (cib, cjt): P(ib) = ib*(516-4ib); jt0(ib) = 8*ib
    int cib = 0;
    while ((cib + 1) * (516 - 4 * (cib + 1)) <= u0) ++cib;
    int cjt = 8 * cib + (u0 - cib * (516 - 4 * cib));

    // hoisted i-fragments: tiles {cib*8 + wid*2, +1}, 128 VGPR
    int myit = cib * 8 + wid * 2;
    bf16x8 bfr0[16], bfr1[16];
    #pragma unroll
    for (int ks = 0; ks < 16; ++ks) {
        bfr0[ks] = F[(myit + 0) * 1024 + ks * 64 + lane];
        bfr1[ks] = F[(myit + 1) * 1024 + ks * 64 + lane];
    }

    auto stage_unit = [&](int jt, uint4* dst) {     // 4 x 16B per thread
        const uint4* gp = F4 + (size_t)jt * 1024;
        #pragma unroll
        for (int q = 0; q < 4; ++q)
            stage16(gp + q * 256 + tid, dst + q * 256 + wid * 64);
    };
    auto stepc = [](int& ib, int& jt) {
        if (++jt == 512) { if (ib < 63) { ++ib; jt = 8 * ib; } else jt = 511; }
    };

    // prologue: stage(u0) [4], pad [1], stage(u0+1) [4] -> vmcnt(5) uniform
    int sib = cib, sjt = cjt;
    stage_unit(sjt, sbuf[0]);
    stage16(F4 + tid, dump);
    stepc(sib, sjt);
    stage_unit(sjt, sbuf[1]);

    float rm0[16], rm1[16];
    #pragma unroll
    for (int r = 0; r < 16; ++r) { rm0[r] = -1e30f; rm1[r] = -1e30f; }

    const bool dvalid = (((L >> 2) & 1) == hi);     // lane holds a diag elem
    const int  dreg   = (L & 3) | ((L >> 3) << 2);  // ...at this acc reg

    // fold rm over j-lanes and flush i-side maxima for i-block fib
    auto flush_i = [&](int fib) {
        #pragma unroll
        for (int r = 0; r < 16; ++r) {
            float a = rm0[r];
            a = fmaxf(a, dpp_rot<0x121>(a));
            a = fmaxf(a, dpp_rot<0x122>(a));
            a = fmaxf(a, dpp_rot<0x124>(a));
            a = fmaxf(a, dpp_rot<0x128>(a));
            rm0[r] = fmaxf(a, __shfl_xor(a, 16, 64));
            float c = rm1[r];
            c = fmaxf(c, dpp_rot<0x121>(c));
            c = fmaxf(c, dpp_rot<0x122>(c));
            c = fmaxf(c, dpp_rot<0x124>(c));
            c = fmaxf(c, dpp_rot<0x128>(c));
            rm1[r] = fmaxf(c, __shfl_xor(c, 16, 64));
        }
        float v0 = rm0[0], v1 = rm1[0];
        #pragma unroll
        for (int r = 1; r < 16; ++r) {
            v0 = (dreg == r) ? rm0[r] : v0;         // lane picks its i-row
            v1 = (dreg == r) ? rm1[r] : v1;
        }
        if (dvalid) {
            int base = fib * 256 + wid * 64;
            atomicMax(&rowcand[base + L],      fkey(v0));
            atomicMax(&rowcand[base + 32 + L], fkey(v1));
        }
    };

    int myib = cib;
    int bsel = 0;
    for (int s = u0; s < uend; ++s) {
        // stage(s) guaranteed done: everything older than the newest 5 vmem
        // ops (1 j-atomic + 4 stage loads of s+1) has retired.
        asm volatile("s_waitcnt vmcnt(5)" ::: "memory");
        __builtin_amdgcn_s_barrier();
        __builtin_amdgcn_sched_barrier(0);

        const int  mjp = cjt;
        const bool mpd = (cjt == myit) || (cjt == myit + 1);
        const bool m0  = (cjt == myit);

        // ---- MFMA: 2 chains ----
        const uint4* sb = &sbuf[bsel][0];
        f32x16 c0 = {0.f}, c1 = {0.f};
        #pragma unroll
        for (int ks = 0; ks < 16; ++ks) {
            bf16x8 af = *(const bf16x8*)(sb + ks * 64 + lane);
            c0 = __builtin_amdgcn_mfma_f32_32x32x16_bf16(bfr0[ks], af, c0, 0, 0, 0);
            c1 = __builtin_amdgcn_mfma_f32_32x32x16_bf16(bfr1[ks], af, c1, 0, 0, 0);
        }

        // ---- EPI: wave-uniform diag fast path; split jm dep chains ----
        float jma = -1e30f, jmb = -1e30f;
        if (mpd) {
            #pragma unroll
            for (int r = 0; r < 16; ++r) {
                float v0 = c0[r], v1 = c1[r];
                if (m0 && dvalid && r == dreg)  v0 = -1e30f;
                if (!m0 && dvalid && r == dreg) v1 = -1e30f;
                rm0[r] = fmaxf(rm0[r], v0);
                rm1[r] = fmaxf(rm1[r], v1);
                if (r & 1) jmb = fmaxf(jmb, fmaxf(v0, v1));
                else       jma = fmaxf(jma, fmaxf(v0, v1));
            }
        } else {
            #pragma unroll
            for (int r = 0; r < 16; ++r) {
                float v0 = c0[r], v1 = c1[r];
                rm0[r] = fmaxf(rm0[r], v0);
                rm1[r] = fmaxf(rm1[r], v1);
                if (r & 1) jmb = fmaxf(jmb, fmaxf(v0, v1));
                else       jma = fmaxf(jma, fmaxf(v0, v1));
            }
        }
        float jm = fmaxf(jma, jmb);
        jm = fmaxf(jm, __shfl_xor(jm, 32, 64));     // merge i-halves
        if (lane < 32) atomicMax(&rowcand[mjp * 32 + L], fkey(jm));

        // advance compute cursor; rare i-block transition
        stepc(cib, cjt);
        if (cib != myib) {
            flush_i(myib);
            #pragma unroll
            for (int r = 0; r < 16; ++r) { rm0[r] = -1e30f; rm1[r] = -1e30f; }
            myib = cib;
            if (s + 1 < uend) {
                myit = cib * 8 + wid * 2;
                #pragma unroll
                for (int ks = 0; ks < 16; ++ks) {
                    bfr0[ks] = F[(myit + 0) * 1024 + ks * 64 + lane];
                    bfr1[ks] = F[(myit + 1) * 1024 + ks * 64 + lane];
                }
            }
        }

        // stage unit s+2 into the retiring slot; tail: clamped re-stage
        __builtin_amdgcn_sched_barrier(0);
        stepc(sib, sjt);
        stage_unit(sjt, &sbuf[bsel + 2 >= 3 ? bsel - 1 : bsel + 2][0]);
        bsel = (bsel + 1 >= 3) ? 0 : bsel + 1;
    }
    flush_i(myib);
}

// ---------------- K3: loss epilogue (2-stage, deterministic) --------------
__global__ __launch_bounds__(256) void kloss1(const unsigned* __restrict__ rowcand,
                                              float* __restrict__ partial) {
    int i = blockIdx.x * 256 + threadIdx.x;         // 64 blocks x 256
    unsigned k = rowcand[i];
    unsigned u = (k & 0x80000000u) ? (k ^ 0x80000000u) : ~k;
    float gv = __builtin_bit_cast(float, u);
    float d = sqrtf(fmaxf(2.f - 2.f * gv, 0.f));
    float acc = logf(d + 1e-8f);
    #pragma unroll
    for (int m = 1; m < 64; m <<= 1) acc += __shfl_xor(acc, m, 64);
    __shared__ float p[4];
    int wid = threadIdx.x >> 6, lane = threadIdx.x & 63;
    if (lane == 0) p[wid] = acc;
    __syncthreads();
    if (threadIdx.x == 0)
        partial[blockIdx.x] = (p[0] + p[1]) + (p[2] + p[3]);
}

__global__ __launch_bounds__(64) void kloss2(const float* __restrict__ partial,
                                             float* __restrict__ out) {
    float acc = partial[threadIdx.x];
    #pragma unroll
    for (int m = 1; m < 64; m <<= 1) acc += __shfl_xor(acc, m, 64);
    if (threadIdx.x == 0) out[0] = -acc / (float)NROWS;
}

extern "C" void kernel_launch(void* const* d_in, const int* in_sizes, int n_in,
                              void* d_out, int out_size, void* d_ws, size_t ws_size,
                              hipStream_t stream) {
    const float* x = (const float*)d_in[0];
    float* out = (float*)d_out;
    char* ws = (char*)d_ws;

    uint4*    F       = (uint4*)ws;                                 // 8 MiB
    unsigned* rowcand = (unsigned*)(ws + 8u * 1024u * 1024u + 65536u); // 64 KiB
    float*    partial = (float*)(ws + 8u * 1024u * 1024u + 131072u);   // 256 B

    knp   <<<NROWS / 32, 256, 0, stream>>>(x, F, rowcand);
    kmax  <<<NBLK, 256, 0, stream>>>((const bf16x8*)F, rowcand);
    kloss1<<<64, 256, 0, stream>>>(rowcand, partial);
    kloss2<<<1, 64, 0, stream>>>(partial, out);
}